// Round 1
// baseline (214.291 us; speedup 1.0000x reference)
//
#include <hip/hip_runtime.h>
#include <math.h>

#define NXC 200   // grid edge
#define NBB 512   // batch
#define SPLIT 4   // blocks per batch in the sums kernel
#define RPB (NXC / SPLIT)  // 50 rows per block

// ---------------------------------------------------------------------------
// Kernel A: per-(batch, row-slab) partial sums. 2048 blocks x 256 threads
// (4 waves). Wave w owns rows il = w + 4k (il < 50). Lane l<50 loads float4
// covering columns 4l..4l+3. Column sums accumulate per-lane in registers;
// row sums are only 3-shuffle-compressed in the loop (8 partials/row to LDS),
// finished after the loop. No boundary handling here -> hot loop is pure
// load + add. 8 blocks/CU for fine-grained balancing.
// ---------------------------------------------------------------------------
__global__ __launch_bounds__(256, 8) void sums_kernel(
    const float* __restrict__ layout, const float* __restrict__ heat,
    float* __restrict__ colh, float* __restrict__ coll,
    float* __restrict__ rowh, float* __restrict__ rowl) {
  const int blk  = blockIdx.x;
  const int b    = blk >> 2;             // batch
  const int r0   = (blk & 3) * RPB;      // first row of this slab
  const int tid  = threadIdx.x;
  const int wave = tid >> 6;             // 0..3
  const int lane = tid & 63;
  const bool act = (lane < 50);

  const float4* __restrict__ hp =
      reinterpret_cast<const float4*>(heat + (size_t)b * NXC * NXC);
  const float4* __restrict__ lp =
      reinterpret_cast<const float4*>(layout + (size_t)b * NXC * NXC);

  __shared__ float s_ph[RPB][8];   // 8 row-sum partials per row (heat)
  __shared__ float s_pl[RPB][8];   // (layout)
  __shared__ float s_hc[4][NXC];   // per-wave column partials (heat)
  __shared__ float s_lc[4][NXC];   // (layout)

  float hc0=0.f,hc1=0.f,hc2=0.f,hc3=0.f;
  float lc0=0.f,lc1=0.f,lc2=0.f,lc3=0.f;

  #pragma unroll
  for (int k = 0; k < 13; ++k) {
    const int il = wave + 4 * k;         // wave-uniform
    if (il < RPB) {
      const int i = r0 + il;
      float4 hv = make_float4(0.f,0.f,0.f,0.f);
      float4 lv = make_float4(0.f,0.f,0.f,0.f);
      if (act) {
        hv = hp[i * 50 + lane];
        lv = lp[i * 50 + lane];
      }
      hc0 += hv.x; hc1 += hv.y; hc2 += hv.z; hc3 += hv.w;
      lc0 += lv.x; lc1 += lv.y; lc2 += lv.z; lc3 += lv.w;

      // 3-deep partial reduce: lanes 0..7 end with stride-8 comb partials
      // whose sum over p=0..7 is the full row sum (inactive lanes carry 0).
      float hs = (hv.x + hv.y) + (hv.z + hv.w);
      float ls = (lv.x + lv.y) + (lv.z + lv.w);
      hs += __shfl_down(hs, 32); ls += __shfl_down(ls, 32);
      hs += __shfl_down(hs, 16); ls += __shfl_down(ls, 16);
      hs += __shfl_down(hs, 8);  ls += __shfl_down(ls, 8);
      if (lane < 8) { s_ph[il][lane] = hs; s_pl[il][lane] = ls; }
    }
  }

  if (act) {
    s_hc[wave][4*lane+0] = hc0; s_hc[wave][4*lane+1] = hc1;
    s_hc[wave][4*lane+2] = hc2; s_hc[wave][4*lane+3] = hc3;
    s_lc[wave][4*lane+0] = lc0; s_lc[wave][4*lane+1] = lc1;
    s_lc[wave][4*lane+2] = lc2; s_lc[wave][4*lane+3] = lc3;
  }
  __syncthreads();

  if (tid < NXC) {
    float a = (s_hc[0][tid] + s_hc[1][tid]) + (s_hc[2][tid] + s_hc[3][tid]);
    float c = (s_lc[0][tid] + s_lc[1][tid]) + (s_lc[2][tid] + s_lc[3][tid]);
    colh[(size_t)blk * NXC + tid] = a;
    coll[(size_t)blk * NXC + tid] = c;
  } else if (tid < NXC + RPB) {
    const int r = tid - NXC;
    float th = 0.f, tl = 0.f;
    #pragma unroll
    for (int p = 0; p < 8; ++p) { th += s_ph[r][p]; tl += s_pl[r][p]; }
    rowh[(size_t)b * NXC + r0 + r] = th;
    rowl[(size_t)b * NXC + r0 + r] = tl;
  }
}

// ---------------------------------------------------------------------------
// Kernel B: per-batch finalize. 512 blocks x 256 threads (4 waves).
// Combines the 4 column-partials, re-reads the 8 boundary rows/cols of heat
// (L2/L3-resident after kernel A), computes dv/dh, per-batch min/max
// normalization, and the OHEM contribution -> one atomicAdd per batch.
// ---------------------------------------------------------------------------
__global__ __launch_bounds__(256, 2) void finalize_kernel(
    const float* __restrict__ heat,
    const float* __restrict__ colh, const float* __restrict__ coll,
    const float* __restrict__ rowh, const float* __restrict__ rowl,
    float* __restrict__ out) {
  const int b    = blockIdx.x;
  const int tid  = threadIdx.x;
  const int wave = tid >> 6;
  const int lane = tid & 63;

  __shared__ float s_CS[NXC];   // total column sums (heat)
  __shared__ float s_CL[NXC];   // total column sums (layout)
  __shared__ float s_RS[NXC];   // row sums (heat)
  __shared__ float s_red[4][4]; // minv/maxv/minh/maxh per wave
  __shared__ float s_sum[4];    // contrib partial per wave

  const float* __restrict__ hb = heat + (size_t)b * NXC * NXC;

  float rl_j = 0.f;
  if (tid < NXC) {
    const size_t cbase = (size_t)b * SPLIT * NXC;
    float a = (colh[cbase + 0*NXC + tid] + colh[cbase + 1*NXC + tid])
            + (colh[cbase + 2*NXC + tid] + colh[cbase + 3*NXC + tid]);
    float c = (coll[cbase + 0*NXC + tid] + coll[cbase + 1*NXC + tid])
            + (coll[cbase + 2*NXC + tid] + coll[cbase + 3*NXC + tid]);
    s_CS[tid] = a;
    s_CL[tid] = c;
    s_RS[tid] = rowh[(size_t)b * NXC + tid];
    rl_j      = rowl[(size_t)b * NXC + tid];
  }
  __syncthreads();

  const float COF = (float)(0.25 * (0.1/199.0) * (0.1/199.0));
  float dv = 0.f, dh = 0.f;
  if (tid < NXC) {
    const int j  = tid;
    const int jm = (j == 0) ? 1 : j - 1;
    const int jp = (j == NXC-1) ? NXC-2 : j + 1;

    // boundary rows 0,1,198,199 (coalesced reads)
    const float h0   = hb[0*NXC + j];
    const float h1   = hb[1*NXC + j];
    const float h198 = hb[198*NXC + j];
    const float h199 = hb[199*NXC + j];
    float Sv = 0.25f * (2.f*s_CS[j]
                        + h1 - h199        // +h[1,j]   - h[199,j]
                        + h198 - h0        // +h[198,j] - h[0,j]
                        + s_CS[jm] + s_CS[jp])
             + COF * s_CL[j];
    dv = fabsf(Sv - s_CS[j]) * (1.f / NXC);

    // boundary cols 0,1,198,199 of row j via two aligned float4 loads
    const float4 c03 = *reinterpret_cast<const float4*>(hb + (size_t)j*NXC);
    const float4 c69 = *reinterpret_cast<const float4*>(hb + (size_t)j*NXC + 196);
    float Sh = 0.25f * (2.f*s_RS[j]
                        + c03.y - c69.w    // +h[j,1]   - h[j,199]
                        + c69.z - c03.x    // +h[j,198] - h[j,0]
                        + s_RS[jm] + s_RS[jp])
             + COF * rl_j;
    dh = fabsf(Sh - s_RS[j]) * (1.f / NXC);
  }

  // per-batch min/max of dv and dh (dv,dh >= 0 so max pad 0 is safe)
  float mnv = (tid < NXC) ? dv : INFINITY;
  float mxv = dv;
  float mnh = (tid < NXC) ? dh : INFINITY;
  float mxh = dh;
  #pragma unroll
  for (int off = 32; off > 0; off >>= 1) {
    mnv = fminf(mnv, __shfl_down(mnv, off));
    mxv = fmaxf(mxv, __shfl_down(mxv, off));
    mnh = fminf(mnh, __shfl_down(mnh, off));
    mxh = fmaxf(mxh, __shfl_down(mxh, off));
  }
  if (lane == 0) {
    s_red[0][wave] = mnv;
    s_red[1][wave] = mxv;
    s_red[2][wave] = mnh;
    s_red[3][wave] = mxh;
  }
  __syncthreads();

  float MNV = INFINITY, MXV = -INFINITY, MNH = INFINITY, MXH = -INFINITY;
  #pragma unroll
  for (int w = 0; w < 4; ++w) {
    MNV = fminf(MNV, s_red[0][w]); MXV = fmaxf(MXV, s_red[1][w]);
    MNH = fminf(MNH, s_red[2][w]); MXH = fmaxf(MXH, s_red[3][w]);
  }

  float contrib = 0.f;
  if (tid < NXC) {
    contrib = 10.f * (dv - MNV) * dv / (MXV - MNV)
            + 10.f * (dh - MNH) * dh / (MXH - MNH);
  }
  #pragma unroll
  for (int off = 32; off > 0; off >>= 1) contrib += __shfl_down(contrib, off);
  if (lane == 0) s_sum[wave] = contrib;
  __syncthreads();
  if (tid == 0) {
    float tot = (s_sum[0] + s_sum[1]) + (s_sum[2] + s_sum[3]);
    atomicAdd(out, tot * (1.f / ((float)NBB * (float)NXC)));
  }
}

extern "C" void kernel_launch(void* const* d_in, const int* in_sizes, int n_in,
                              void* d_out, int out_size, void* d_ws, size_t ws_size,
                              hipStream_t stream) {
  const float* layout = (const float*)d_in[0];
  const float* heat   = (const float*)d_in[1];
  float* out = (float*)d_out;

  // workspace layout (floats): colh[2048*200] coll[2048*200]
  //                            rowh[512*200]  rowl[512*200]   (~4.1 MB)
  float* ws   = (float*)d_ws;
  float* colh = ws;
  float* coll = colh + (size_t)NBB * SPLIT * NXC;
  float* rowh = coll + (size_t)NBB * SPLIT * NXC;
  float* rowl = rowh + (size_t)NBB * NXC;

  // d_out is poisoned to 0xAA before every timed launch — zero it first.
  hipMemsetAsync(out, 0, (size_t)out_size * sizeof(float), stream);
  sums_kernel<<<NBB * SPLIT, 256, 0, stream>>>(layout, heat, colh, coll, rowh, rowl);
  finalize_kernel<<<NBB, 256, 0, stream>>>(heat, colh, coll, rowh, rowl, out);
}